// Round 13
// baseline (1652.452 us; speedup 1.0000x reference)
//
#include <hip/hip_runtime.h>

#define NN 10000
#define BB 8
#define MROWS 80000   // BB*NN

typedef float f32x4 __attribute__((ext_vector_type(4)));
typedef unsigned int u32x4 __attribute__((ext_vector_type(4)));
typedef _Float16 f16;
typedef _Float16 f16x8 __attribute__((ext_vector_type(8)));

typedef __attribute__((address_space(1))) void as1_void;
typedef __attribute__((address_space(3))) void as3_void;

static __device__ __forceinline__ void gl_lds16(const void* g, void* l){
  __builtin_amdgcn_global_load_lds((as1_void*)g, (as3_void*)l, 16, 0, 0);
}

// ---------------- CSR build (rows padded to even length, zero-weight pads) ----------------
__global__ void k_count(const int* __restrict__ dst, int E, int* __restrict__ counts){
  int i = blockIdx.x * blockDim.x + threadIdx.x;
  if(i < E) atomicAdd(&counts[dst[i]], 1);
}

// rp2 = exclusive scan of round-up-to-2(counts)
__global__ void k_scan(const int* __restrict__ counts, int* __restrict__ rp2){
  __shared__ int buf[1024];
  __shared__ int carry;
  const int t = threadIdx.x;
  if(t == 0){ carry = 0; rp2[0] = 0; }
  __syncthreads();
  for(int base = 0; base < NN; base += 1024){
    int v = (base + t < NN) ? ((counts[base + t] + 1) & ~1) : 0;
    buf[t] = v;
    __syncthreads();
    for(int off = 1; off < 1024; off <<= 1){
      int x = (t >= off) ? buf[t - off] : 0;
      __syncthreads();
      buf[t] += x;
      __syncthreads();
    }
    if(base + t < NN) rp2[base + t + 1] = carry + buf[t];
    __syncthreads();
    if(t == 0) carry += buf[1023];
    __syncthreads();
  }
}

__global__ void k_fill(const int* __restrict__ dst, int E, const int* __restrict__ rp2,
                       int* __restrict__ cursor, int* __restrict__ ci){
  int i = blockIdx.x * blockDim.x + threadIdx.x;
  if(i < E){
    int d = dst[i];
    int p = rp2[d] + atomicAdd(&cursor[d], 1);
    ci[p] = i;   // edge id; rows sorted deterministically afterwards
  }
}

// sort each row's edge ids (deterministic), emit packed (src, wbits) pairs + zero pads
__global__ void k_sort_rows(const int* __restrict__ rp2, const int* __restrict__ cursor,
                            int* __restrict__ ci, unsigned int* __restrict__ ev,
                            const int* __restrict__ esrc, const float* __restrict__ ew){
  const int n = blockIdx.x * blockDim.x + threadIdx.x;
  if(n >= NN) return;
  const int s = rp2[n];
  const int deg = cursor[n];
  const int e = s + deg;
  for(int i = s; i < e - 1; ++i){           // selection sort by edge id (unique) -> deterministic
    int mj = i, mv = ci[i];
    for(int j = i + 1; j < e; ++j){
      int v = ci[j];
      if(v < mv){ mv = v; mj = j; }
    }
    ci[mj] = ci[i]; ci[i] = mv;
  }
  for(int p = s; p < e; ++p){
    int eid = ci[p];
    ev[2 * p]     = (unsigned int)esrc[eid];
    ev[2 * p + 1] = __float_as_uint(ew[eid]);
  }
  const int e2 = rp2[n + 1];
  for(int p = e; p < e2; ++p){              // zero-weight pads (even row length)
    ev[2 * p]     = 0u;
    ev[2 * p + 1] = 0u;
  }
}

// ---------------- f32 -> fp16 convert (8 at a time) ----------------
__global__ void k_cvt(const float4* __restrict__ in, f16x8* __restrict__ out, int n8){
  int i = blockIdx.x * blockDim.x + threadIdx.x;
  if(i >= n8) return;
  float4 v0 = in[2 * i], v1 = in[2 * i + 1];
  f16x8 o;
  o[0] = (f16)v0.x; o[1] = (f16)v0.y; o[2] = (f16)v0.z; o[3] = (f16)v0.w;
  o[4] = (f16)v1.x; o[5] = (f16)v1.y; o[6] = (f16)v1.z; o[7] = (f16)v1.w;
  out[i] = o;
}

// Pack weights transposed to fp16: Wt[c][k] = W[k][c].
__global__ void k_pack_w(const float* __restrict__ Wi, const float* __restrict__ LWi,
                         const float* __restrict__ Wb, const float* __restrict__ LWb,
                         f16* __restrict__ dh){
  const int T0 = 512 * 512;
  const int TOT = T0 + 12 * 512 * 256;
  int i = blockIdx.x * blockDim.x + threadIdx.x;
  if(i >= TOT) return;
  float v;
  if(i < T0){
    int c = i >> 9, k = i & 511;
    v = (c < 256) ? Wi[k * 256 + c] : LWi[k * 256 + (c - 256)];
  } else {
    int j = i - T0;
    int li = j >> 17;          // 512*256 = 2^17
    int r = j & 131071;
    int c = r >> 8, k = r & 255;
    const float* src = (c < 256) ? (Wb + (size_t)li * 65536) : (LWb + (size_t)li * 65536);
    v = src[k * 256 + (c & 255)];
  }
  dh[i] = (f16)v;
}

// ---------------- dual GEMM (fp16), K=512 layer-0 only (R12 proven) ----
__global__ __launch_bounds__(256) void k_gemm_dual(
    const f16* __restrict__ A, const f16* __restrict__ Bt,
    f16* __restrict__ Sup, f16* __restrict__ Loc, int K, int nblk)
{
  __shared__ char smem[40960];   // union: staging (As 2x4KB @0, Bs 2x16KB @8192) | bounce 33KB
  const int t = threadIdx.x;
  const int pid = blockIdx.x;
  const int q = nblk >> 3, r = nblk & 7;
  const int xcd = pid & 7, sl = pid >> 3;
  const int wg = (xcd < r ? xcd * (q + 1) : r * (q + 1) + (xcd - r) * q) + sl;
  const int m0 = (wg >> 1) << 6;
  const int by = wg & 1;
  const int n0 = by << 8;
  const int lane = t & 63, wv = t >> 6;
  const int rA = lane & 15, g = lane >> 4;
  f32x4 acc[4][4] = {};
  const int nsteps = K >> 5;
  const int rowt = t >> 2;                         // 0..63
  const int csw  = (t & 3) ^ ((rowt >> 1) & 3);    // pre-swizzled source chunk
  const int cbt  = csw << 3;                       // f16 offset 0/8/16/24

  auto STAGE = [&](int s, int buf){
    const int k0 = s << 5;
    const size_t aoff = (size_t)(m0 + rowt) * K + k0 + cbt;
    gl_lds16(A + aoff, smem + buf * 4096 + t * 16);
    #pragma unroll
    for(int qq = 0; qq < 4; ++qq){
      const size_t boff = (size_t)(n0 + qq * 64 + rowt) * K + k0 + cbt;
      gl_lds16(Bt + boff, smem + 8192 + buf * 16384 + qq * 4096 + t * 16);
    }
  };

  STAGE(0, 0);
  int cur = 0;
  const int slotx = (rA >> 1) & 3;        // read-side XOR base

  for(int s = 0; s < nsteps; ++s){
    __builtin_amdgcn_sched_barrier(0);
    if(s + 1 < nsteps){
      STAGE(s + 1, cur ^ 1);
      asm volatile("s_waitcnt vmcnt(5)" ::: "memory");
    } else {
      asm volatile("s_waitcnt vmcnt(0)" ::: "memory");
    }
    __builtin_amdgcn_s_barrier();
    __builtin_amdgcn_sched_barrier(0);

    f16x8 av[4], bv[4];
    const f16* AsC = (const f16*)(smem + cur * 4096);
    const f16* BsC = (const f16*)(smem + 8192 + cur * 16384);
    #pragma unroll
    for(int mi = 0; mi < 4; ++mi){
      const int ao = (mi * 16 + rA) * 32 + ((g ^ slotx) << 3);
      av[mi] = *(const f16x8*)(AsC + ao);
    }
    #pragma unroll
    for(int ni = 0; ni < 4; ++ni){
      const int bo = wv * 2048 + (ni * 16 + rA) * 32 + ((g ^ slotx) << 3);
      bv[ni] = *(const f16x8*)(BsC + bo);
    }
    #pragma unroll
    for(int mi = 0; mi < 4; ++mi){
      #pragma unroll
      for(int ni = 0; ni < 4; ++ni){
        acc[mi][ni] = __builtin_amdgcn_mfma_f32_16x16x32_f16(av[mi], bv[ni], acc[mi][ni], 0, 0, 0);
      }
    }
    __builtin_amdgcn_sched_barrier(0);
    __builtin_amdgcn_s_barrier();
    cur ^= 1;
  }

  // ---- LDS-bounce epilogue ----
  __syncthreads();
  f16* bounce = (f16*)smem;                // [64 rows][stride 264 f16] = 33 KB
  const int SP = 264;
  const int wn = wv << 6;
  #pragma unroll
  for(int mi = 0; mi < 4; ++mi){
    #pragma unroll
    for(int ni = 0; ni < 4; ++ni){
      const int col = wn + ni * 16 + rA;
      #pragma unroll
      for(int r2 = 0; r2 < 4; ++r2){
        bounce[(mi * 16 + g * 4 + r2) * SP + col] = (f16)acc[mi][ni][r2];
      }
    }
  }
  __syncthreads();
  f16* dstp = ((by == 0) ? Sup : Loc) + (size_t)m0 * 256;
  #pragma unroll
  for(int rr = 0; rr < 8; ++rr){
    const int e = rr * 2048 + t * 8;
    const int row = e >> 8, col = e & 255;
    const f16x8 v = *(const f16x8*)(bounce + row * SP + col);
    *(f16x8*)(dstp + e) = v;
  }
}

// ---------------- barrier-free persistent-B GEMM, K=256 mid layers ----------------
// 512 blocks x 4 waves = 2048 waves. Wave: strip = gw&7 (64 of 512 fused cols;
// strips 0-3 -> Sup, 4-7 -> Loc), m-chunk = gw>>3 grid-strides over 5000 16-row
// tiles. B strip (64x256 f16) lives in 128 VGPR (breg, statically indexed).
// Per m-tile: 8 global A loads + 32 MFMA; NO s_barrier anywhere. Stores bounce
// through wave-private LDS (in-order DS + lgkmcnt only) -> 2 x 16B stores/lane.
__global__ __launch_bounds__(256) void k_gemm_regB(
    const f16* __restrict__ A, const f16* __restrict__ Bt,
    f16* __restrict__ Sup, f16* __restrict__ Loc)
{
  __shared__ f16 bnc[4][16 * 72];        // per-wave bounce, row stride 72 (pad 8)
  const int t = threadIdx.x;
  const int wv = t >> 6, lane = t & 63;
  const int gw = blockIdx.x * 4 + wv;    // 0..2047
  const int strip = gw & 7;
  const int chunk = gw >> 3;             // 0..255
  const int rA = lane & 15, g = lane >> 4;
  f16* dst = (strip < 4) ? Sup : Loc;
  const int dc0 = (strip & 3) << 6;

  // B strip -> registers: breg[tt*8+ss] = Bt[strip*64 + tt*16 + rA][ss*32 + g*8 ..+7]
  f16x8 breg[32];
  {
    const f16* bp = Bt + (size_t)((strip << 6) + rA) * 256 + g * 8;
    #pragma unroll
    for(int tt = 0; tt < 4; ++tt){
      #pragma unroll
      for(int ss = 0; ss < 8; ++ss){
        breg[tt * 8 + ss] = *(const f16x8*)(bp + (size_t)tt * 16 * 256 + ss * 32);
      }
    }
  }

  const int rowrd = lane >> 2;           // readback row (0..15)
  const int colrd = (lane & 3) << 4;     // readback col base (f16)
  f16* mybnc = bnc[wv];

  for(int mt = chunk; mt < 5000; mt += 256){
    const f16* ap = A + (size_t)(mt * 16 + rA) * 256 + g * 8;
    f16x8 av[8];
    #pragma unroll
    for(int ss = 0; ss < 8; ++ss) av[ss] = *(const f16x8*)(ap + ss * 32);
    f32x4 acc[4] = {};
    #pragma unroll
    for(int ss = 0; ss < 8; ++ss){
      #pragma unroll
      for(int tt = 0; tt < 4; ++tt){
        acc[tt] = __builtin_amdgcn_mfma_f32_16x16x32_f16(av[ss], breg[tt * 8 + ss], acc[tt], 0, 0, 0);
      }
    }
    // bounce acc -> wave-private LDS (write col = tt*16+rA, rows g*4+r2)
    #pragma unroll
    for(int tt = 0; tt < 4; ++tt){
      #pragma unroll
      for(int r2 = 0; r2 < 4; ++r2){
        mybnc[(g * 4 + r2) * 72 + tt * 16 + rA] = (f16)acc[tt][r2];
      }
    }
    asm volatile("s_waitcnt lgkmcnt(0)" ::: "memory");   // in-order DS pipe; wave-private
    const f16x8 v0 = *(const f16x8*)(mybnc + rowrd * 72 + colrd);
    const f16x8 v1 = *(const f16x8*)(mybnc + rowrd * 72 + colrd + 8);
    f16* dp = dst + (size_t)(mt * 16 + rowrd) * 256 + dc0 + colrd;
    *(f16x8*)dp = v0;
    *(f16x8*)(dp + 8) = v1;
    asm volatile("s_waitcnt lgkmcnt(0)" ::: "memory");   // reads done before next overwrite
  }
}

// ---------------- aggregation: direct gather, XCD-batch-pinned, D-QUARTER phases -------------
// mode 0: Hnext = fp16(t) ; mode 2: Hnext = fp16((Hprev+t)*0.5) ; mode 3: hout = (Hprev+t)*0.5
__global__ __launch_bounds__(256) void k_agg_q(
    const f16* __restrict__ Sup, const f16* __restrict__ Loc,
    const float* __restrict__ bias,
    const int* __restrict__ rp2, const unsigned int* __restrict__ ev,
    const f16* __restrict__ Hprev, f16* __restrict__ Hnext,
    float* __restrict__ hout, const int mode)
{
  const int pid = blockIdx.x;
  const int b = pid & 7;
  const int rest = pid >> 3;           // 0..1251
  const int grp = rest % 313;
  const int qd  = rest / 313;          // 0..3
  const int t = threadIdx.x;
  const int j = t >> 3;                // node in group (0..31)
  const int l = t & 7;
  const int n = grp * 32 + j;
  if(n >= NN) return;
  const int d0 = (qd << 6) + (l << 3);
  const size_t rb = ((size_t)b * NN + n) * 256 + d0;
  float a[8];
  {
    const f16x8 lv = *(const f16x8*)(Loc + rb);
    float4 q0 = *(const float4*)(bias + d0);
    float4 q1 = *(const float4*)(bias + d0 + 4);
    a[0] = (float)lv[0] + q0.x; a[1] = (float)lv[1] + q0.y;
    a[2] = (float)lv[2] + q0.z; a[3] = (float)lv[3] + q0.w;
    a[4] = (float)lv[4] + q1.x; a[5] = (float)lv[5] + q1.y;
    a[6] = (float)lv[6] + q1.z; a[7] = (float)lv[7] + q1.w;
  }
  const int s = rp2[n], e = rp2[n + 1];
  const size_t bb = (size_t)b * NN * 256 + d0;
  for(int i = s; i < e; i += 2){
    const u32x4 ee = *(const u32x4*)(ev + 2 * i);   // 2 edges; same addr for 8 lanes (dedup)
    const float w0 = __uint_as_float(ee[1]);
    const float w1 = __uint_as_float(ee[3]);
    const f16x8 h0 = *(const f16x8*)(Sup + bb + ((size_t)(int)ee[0]) * 256);
    const f16x8 h1 = *(const f16x8*)(Sup + bb + ((size_t)(int)ee[2]) * 256);
    #pragma unroll
    for(int d = 0; d < 8; ++d){
      a[d] = fmaf(w0, (float)h0[d], a[d]);
      a[d] = fmaf(w1, (float)h1[d], a[d]);
    }
  }
  if(mode >= 2){
    const f16x8 hp = *(const f16x8*)(Hprev + rb);
    #pragma unroll
    for(int d = 0; d < 8; ++d) a[d] = (a[d] + (float)hp[d]) * 0.5f;
  }
  if(mode == 3){
    f32x4 o0 = {a[0], a[1], a[2], a[3]};
    f32x4 o1 = {a[4], a[5], a[6], a[7]};
    *(f32x4*)(hout + rb) = o0;
    *(f32x4*)(hout + rb + 4) = o1;
    return;
  }
  f16x8 o;
  #pragma unroll
  for(int d = 0; d < 8; ++d) o[d] = (f16)a[d];
  *(f16x8*)(Hnext + rb) = o;
}

// ---------------- output layer (Dout=3), f32 throughout ----------------
__global__ __launch_bounds__(256) void k_out_sup(const float* __restrict__ h,
    const float* __restrict__ Wo, float* __restrict__ sup3){
  const int gid = blockIdx.x * 4 + (threadIdx.x >> 6);
  const int lane = threadIdx.x & 63;
  if(gid >= MROWS) return;
  const float4 v = *(const float4*)(h + (size_t)gid * 256 + lane * 4);
  const float hv[4] = {v.x, v.y, v.z, v.w};
  float p0 = 0.f, p1 = 0.f, p2 = 0.f;
  #pragma unroll
  for(int j = 0; j < 4; ++j){
    const int k = lane * 4 + j;
    p0 = fmaf(hv[j], Wo[k * 3 + 0], p0);
    p1 = fmaf(hv[j], Wo[k * 3 + 1], p1);
    p2 = fmaf(hv[j], Wo[k * 3 + 2], p2);
  }
  #pragma unroll
  for(int off = 32; off; off >>= 1){
    p0 += __shfl_xor(p0, off, 64);
    p1 += __shfl_xor(p1, off, 64);
    p2 += __shfl_xor(p2, off, 64);
  }
  if(lane == 0){
    float* o = sup3 + (size_t)gid * 3;
    o[0] = p0; o[1] = p1; o[2] = p2;
  }
}

__global__ __launch_bounds__(256) void k_out_final(const float* __restrict__ h,
    const float* __restrict__ LWo, const float* __restrict__ bo,
    const int* __restrict__ rp2, const unsigned int* __restrict__ ev,
    const float* __restrict__ sup3, float* __restrict__ out){
  const int gid = blockIdx.x * 4 + (threadIdx.x >> 6);
  const int lane = threadIdx.x & 63;
  if(gid >= MROWS) return;
  const int b = gid / NN, n = gid % NN;
  const float4 v = *(const float4*)(h + (size_t)gid * 256 + lane * 4);
  const float hv[4] = {v.x, v.y, v.z, v.w};
  float p0 = 0.f, p1 = 0.f, p2 = 0.f;
  #pragma unroll
  for(int j = 0; j < 4; ++j){
    const int k = lane * 4 + j;
    p0 = fmaf(hv[j], LWo[k * 3 + 0], p0);
    p1 = fmaf(hv[j], LWo[k * 3 + 1], p1);
    p2 = fmaf(hv[j], LWo[k * 3 + 2], p2);
  }
  const int s = rp2[n], e = rp2[n + 1];
  for(int i = s + lane; i < e; i += 64){
    const int src = (int)ev[2 * i];
    const float w = __uint_as_float(ev[2 * i + 1]);
    const float* sp = sup3 + ((size_t)b * NN + src) * 3;
    p0 = fmaf(w, sp[0], p0);
    p1 = fmaf(w, sp[1], p1);
    p2 = fmaf(w, sp[2], p2);
  }
  #pragma unroll
  for(int off = 32; off; off >>= 1){
    p0 += __shfl_xor(p0, off, 64);
    p1 += __shfl_xor(p1, off, 64);
    p2 += __shfl_xor(p2, off, 64);
  }
  if(lane == 0){
    float* o = out + (size_t)gid * 3;
    o[0] = p0 + bo[0]; o[1] = p1 + bo[1]; o[2] = p2 + bo[2];
  }
}

// ---------------- host ----------------
extern "C" void kernel_launch(void* const* d_in, const int* in_sizes, int n_in,
                              void* d_out, int out_size, void* d_ws, size_t ws_size,
                              hipStream_t stream) {
  const float* x     = (const float*)d_in[0];
  const int*   esrc  = (const int*)d_in[1];
  const int*   edst  = (const int*)d_in[2];
  const float* ew    = (const float*)d_in[3];
  const float* W_in  = (const float*)d_in[4];
  const float* LW_in = (const float*)d_in[5];
  const float* b_in  = (const float*)d_in[6];
  const float* W_blk = (const float*)d_in[7];
  const float* LW_blk= (const float*)d_in[8];
  const float* b_blk = (const float*)d_in[9];
  const float* W_out = (const float*)d_in[10];
  const float* LW_out= (const float*)d_in[11];
  const float* b_out = (const float*)d_in[12];
  const int E = in_sizes[1];

  float* outF  = (float*)d_out;
  float* xout  = outF;                  // [B,N,3]
  float* hOut  = outF + 240000;         // h region [B,N,256] f32, written at last layer
  f16* x16 = (f16*)hOut;                // doubles as fp16-x scratch before layer 0

  char* ws = (char*)d_ws;
  size_t off = 0;
  auto alloc = [&](size_t bytes) -> char* {
    char* p = ws + off;
    off += (bytes + 255) & ~(size_t)255;
    return p;
  };
  const size_t HB = (size_t)20480000 * 2;           // one fp16 activation buffer
  f16* Ha  = (f16*)alloc(HB);
  f16* Hb  = (f16*)alloc(HB);
  f16* Sup = (f16*)alloc(HB);                       // row-major [b*NN+n][256]
  f16* Loc = (f16*)alloc(HB);
  const int WTOT = 512 * 512 + 12 * 512 * 256;
  f16* Wt = (f16*)alloc((size_t)WTOT * 2);
  float* sup3    = (float*)alloc((size_t)240000 * 4);
  int*   counts  = (int*)alloc((size_t)2 * NN * 4);   // counts + cursor contiguous
  int*   cursor  = counts + NN;
  int*   rp2     = (int*)alloc((size_t)(NN + 1) * 4);
  int*   ci      = (int*)alloc((size_t)(E + NN) * 4);
  unsigned int* ev = (unsigned int*)alloc((size_t)2 * (E + NN) * 4);
  (void)ws_size; (void)n_in; (void)out_size;

  // CSR build (deterministic: rows sorted by edge id; even-padded with w=0)
  hipMemsetAsync(counts, 0, (size_t)2 * NN * 4, stream);
  k_count<<<(E + 255) / 256, 256, 0, stream>>>(edst, E, counts);
  k_scan<<<1, 1024, 0, stream>>>(counts, rp2);
  k_fill<<<(E + 255) / 256, 256, 0, stream>>>(edst, E, rp2, cursor, ci);
  k_sort_rows<<<(NN + 255) / 256, 256, 0, stream>>>(rp2, cursor, ci, ev, esrc, ew);

  // convert x -> fp16 ; pack transposed weights fp16
  k_cvt<<<(5120000 + 255) / 256, 256, 0, stream>>>((const float4*)x, (f16x8*)x16, 5120000);
  k_pack_w<<<(WTOT + 255) / 256, 256, 0, stream>>>(W_in, LW_in, W_blk, LW_blk, Wt);

  const int NBLK = 2500;    // layer-0 GEMM: 1250 m-blocks x 2 (Sup/Loc)
  const int GBLK = 512;     // regB GEMM: 2048 waves
  const int ABLK = 10016;   // agg: 4 quarters x 313 groups x 8 batches
  // layer 0 (K=512): h0 = t
  k_gemm_dual<<<NBLK, 256, 0, stream>>>(x16, Wt, Sup, Loc, 512, NBLK);
  k_agg_q<<<ABLK, 256, 0, stream>>>(Sup, Loc, b_in, rp2, ev, Ha, Ha, xout, 0);

  const f16* Wm = Wt + 512 * 512;
  for(int l = 0; l < 6; ++l){
    const int li0 = 2 * l, li1 = 2 * l + 1;
    k_gemm_regB<<<GBLK, 256, 0, stream>>>(Ha, Wm + (size_t)li0 * 131072, Sup, Loc);
    k_agg_q<<<ABLK, 256, 0, stream>>>(Sup, Loc, b_blk + li0 * 256, rp2, ev, Ha, Hb, xout, 0);
    k_gemm_regB<<<GBLK, 256, 0, stream>>>(Hb, Wm + (size_t)li1 * 131072, Sup, Loc);
    k_agg_q<<<ABLK, 256, 0, stream>>>(Sup, Loc, b_blk + li1 * 256, rp2, ev, Ha, Ha, hOut, (l == 5) ? 3 : 2);
  }

  // output layer, f32 from hOut (d_out h region)
  k_out_sup<<<MROWS / 4, 256, 0, stream>>>(hOut, W_out, sup3);
  k_out_final<<<MROWS / 4, 256, 0, stream>>>(hOut, LW_out, b_out, rp2, ev, sup3, xout);
}

// Round 14
// 1463.569 us; speedup vs baseline: 1.1291x; 1.1291x over previous
//
#include <hip/hip_runtime.h>

#define NN 10000
#define BB 8
#define MROWS 80000   // BB*NN

typedef float f32x4 __attribute__((ext_vector_type(4)));
typedef unsigned int u32x4 __attribute__((ext_vector_type(4)));
typedef _Float16 f16;
typedef _Float16 f16x8 __attribute__((ext_vector_type(8)));

typedef __attribute__((address_space(1))) void as1_void;
typedef __attribute__((address_space(3))) void as3_void;

static __device__ __forceinline__ void gl_lds16(const void* g, void* l){
  __builtin_amdgcn_global_load_lds((as1_void*)g, (as3_void*)l, 16, 0, 0);
}

// ---------------- CSR build (rows padded to even length, zero-weight pads) ----------------
__global__ void k_count(const int* __restrict__ dst, int E, int* __restrict__ counts){
  int i = blockIdx.x * blockDim.x + threadIdx.x;
  if(i < E) atomicAdd(&counts[dst[i]], 1);
}

// rp2 = exclusive scan of round-up-to-2(counts)
__global__ void k_scan(const int* __restrict__ counts, int* __restrict__ rp2){
  __shared__ int buf[1024];
  __shared__ int carry;
  const int t = threadIdx.x;
  if(t == 0){ carry = 0; rp2[0] = 0; }
  __syncthreads();
  for(int base = 0; base < NN; base += 1024){
    int v = (base + t < NN) ? ((counts[base + t] + 1) & ~1) : 0;
    buf[t] = v;
    __syncthreads();
    for(int off = 1; off < 1024; off <<= 1){
      int x = (t >= off) ? buf[t - off] : 0;
      __syncthreads();
      buf[t] += x;
      __syncthreads();
    }
    if(base + t < NN) rp2[base + t + 1] = carry + buf[t];
    __syncthreads();
    if(t == 0) carry += buf[1023];
    __syncthreads();
  }
}

__global__ void k_fill(const int* __restrict__ dst, int E, const int* __restrict__ rp2,
                       int* __restrict__ cursor, int* __restrict__ ci){
  int i = blockIdx.x * blockDim.x + threadIdx.x;
  if(i < E){
    int d = dst[i];
    int p = rp2[d] + atomicAdd(&cursor[d], 1);
    ci[p] = i;   // edge id; rows sorted deterministically afterwards
  }
}

// sort each row's edge ids (deterministic), emit packed (src, wbits) pairs + zero pads
__global__ void k_sort_rows(const int* __restrict__ rp2, const int* __restrict__ cursor,
                            int* __restrict__ ci, unsigned int* __restrict__ ev,
                            const int* __restrict__ esrc, const float* __restrict__ ew){
  const int n = blockIdx.x * blockDim.x + threadIdx.x;
  if(n >= NN) return;
  const int s = rp2[n];
  const int deg = cursor[n];
  const int e = s + deg;
  for(int i = s; i < e - 1; ++i){           // selection sort by edge id (unique) -> deterministic
    int mj = i, mv = ci[i];
    for(int j = i + 1; j < e; ++j){
      int v = ci[j];
      if(v < mv){ mv = v; mj = j; }
    }
    ci[mj] = ci[i]; ci[i] = mv;
  }
  for(int p = s; p < e; ++p){
    int eid = ci[p];
    ev[2 * p]     = (unsigned int)esrc[eid];
    ev[2 * p + 1] = __float_as_uint(ew[eid]);
  }
  const int e2 = rp2[n + 1];
  for(int p = e; p < e2; ++p){              // zero-weight pads (even row length)
    ev[2 * p]     = 0u;
    ev[2 * p + 1] = 0u;
  }
}

// ---------------- f32 -> fp16 convert (8 at a time) ----------------
__global__ void k_cvt(const float4* __restrict__ in, f16x8* __restrict__ out, int n8){
  int i = blockIdx.x * blockDim.x + threadIdx.x;
  if(i >= n8) return;
  float4 v0 = in[2 * i], v1 = in[2 * i + 1];
  f16x8 o;
  o[0] = (f16)v0.x; o[1] = (f16)v0.y; o[2] = (f16)v0.z; o[3] = (f16)v0.w;
  o[4] = (f16)v1.x; o[5] = (f16)v1.y; o[6] = (f16)v1.z; o[7] = (f16)v1.w;
  out[i] = o;
}

// Pack weights transposed to fp16: Wt[c][k] = W[k][c].
__global__ void k_pack_w(const float* __restrict__ Wi, const float* __restrict__ LWi,
                         const float* __restrict__ Wb, const float* __restrict__ LWb,
                         f16* __restrict__ dh){
  const int T0 = 512 * 512;
  const int TOT = T0 + 12 * 512 * 256;
  int i = blockIdx.x * blockDim.x + threadIdx.x;
  if(i >= TOT) return;
  float v;
  if(i < T0){
    int c = i >> 9, k = i & 511;
    v = (c < 256) ? Wi[k * 256 + c] : LWi[k * 256 + (c - 256)];
  } else {
    int j = i - T0;
    int li = j >> 17;          // 512*256 = 2^17
    int r = j & 131071;
    int c = r >> 8, k = r & 255;
    const float* src = (c < 256) ? (Wb + (size_t)li * 65536) : (LWb + (size_t)li * 65536);
    v = src[k * 256 + (c & 255)];
  }
  dh[i] = (f16)v;
}

// ---------------- dual GEMM (fp16): by=0 -> Sup, by=1 -> Loc ----
// BM=64, BN=256, BK=32; 40KB LDS dbuf -> 4 blocks/CU; counted vmcnt(5).
// LDS-bounce epilogue -> 8 coalesced dwordx4 stores/thread.
__global__ __launch_bounds__(256) void k_gemm_dual(
    const f16* __restrict__ A, const f16* __restrict__ Bt,
    f16* __restrict__ Sup, f16* __restrict__ Loc, int K, int nblk)
{
  __shared__ char smem[40960];   // union: staging (As 2x4KB @0, Bs 2x16KB @8192) | bounce 33KB
  const int t = threadIdx.x;
  const int pid = blockIdx.x;
  const int q = nblk >> 3, r = nblk & 7;
  const int xcd = pid & 7, sl = pid >> 3;
  const int wg = (xcd < r ? xcd * (q + 1) : r * (q + 1) + (xcd - r) * q) + sl;
  const int m0 = (wg >> 1) << 6;
  const int by = wg & 1;
  const int n0 = by << 8;
  const int lane = t & 63, wv = t >> 6;
  const int rA = lane & 15, g = lane >> 4;
  f32x4 acc[4][4] = {};
  const int nsteps = K >> 5;
  const int rowt = t >> 2;                         // 0..63
  const int csw  = (t & 3) ^ ((rowt >> 1) & 3);    // pre-swizzled source chunk
  const int cbt  = csw << 3;                       // f16 offset 0/8/16/24

  auto STAGE = [&](int s, int buf){
    const int k0 = s << 5;
    const size_t aoff = (size_t)(m0 + rowt) * K + k0 + cbt;
    gl_lds16(A + aoff, smem + buf * 4096 + t * 16);
    #pragma unroll
    for(int qq = 0; qq < 4; ++qq){
      const size_t boff = (size_t)(n0 + qq * 64 + rowt) * K + k0 + cbt;
      gl_lds16(Bt + boff, smem + 8192 + buf * 16384 + qq * 4096 + t * 16);
    }
  };

  STAGE(0, 0);
  int cur = 0;
  const int slotx = (rA >> 1) & 3;        // read-side XOR base

  for(int s = 0; s < nsteps; ++s){
    __builtin_amdgcn_sched_barrier(0);
    if(s + 1 < nsteps){
      STAGE(s + 1, cur ^ 1);
      asm volatile("s_waitcnt vmcnt(5)" ::: "memory");
    } else {
      asm volatile("s_waitcnt vmcnt(0)" ::: "memory");
    }
    __builtin_amdgcn_s_barrier();
    __builtin_amdgcn_sched_barrier(0);

    f16x8 av[4], bv[4];
    const f16* AsC = (const f16*)(smem + cur * 4096);
    const f16* BsC = (const f16*)(smem + 8192 + cur * 16384);
    #pragma unroll
    for(int mi = 0; mi < 4; ++mi){
      const int ao = (mi * 16 + rA) * 32 + ((g ^ slotx) << 3);
      av[mi] = *(const f16x8*)(AsC + ao);
    }
    #pragma unroll
    for(int ni = 0; ni < 4; ++ni){
      const int bo = wv * 2048 + (ni * 16 + rA) * 32 + ((g ^ slotx) << 3);
      bv[ni] = *(const f16x8*)(BsC + bo);
    }
    #pragma unroll
    for(int mi = 0; mi < 4; ++mi){
      #pragma unroll
      for(int ni = 0; ni < 4; ++ni){
        acc[mi][ni] = __builtin_amdgcn_mfma_f32_16x16x32_f16(av[mi], bv[ni], acc[mi][ni], 0, 0, 0);
      }
    }
    __builtin_amdgcn_sched_barrier(0);
    __builtin_amdgcn_s_barrier();
    cur ^= 1;
  }

  // ---- LDS-bounce epilogue: acc -> padded LDS tile -> coalesced wide stores ----
  __syncthreads();                         // staging fully consumed; reuse smem
  f16* bounce = (f16*)smem;                // [64 rows][stride 264 f16] = 33 KB
  const int SP = 264;
  const int wn = wv << 6;
  #pragma unroll
  for(int mi = 0; mi < 4; ++mi){
    #pragma unroll
    for(int ni = 0; ni < 4; ++ni){
      const int col = wn + ni * 16 + rA;
      #pragma unroll
      for(int r2 = 0; r2 < 4; ++r2){
        bounce[(mi * 16 + g * 4 + r2) * SP + col] = (f16)acc[mi][ni][r2];
      }
    }
  }
  __syncthreads();
  f16* dstp = ((by == 0) ? Sup : Loc) + (size_t)m0 * 256;
  #pragma unroll
  for(int rr = 0; rr < 8; ++rr){
    const int e = rr * 2048 + t * 8;
    const int row = e >> 8, col = e & 255;
    const f16x8 v = *(const f16x8*)(bounce + row * SP + col);
    *(f16x8*)(dstp + e) = v;
  }
}

// ---------------- aggregation: direct gather, XCD-batch-pinned, D-QUARTER phases -------------
// grid = 10016 blocks: pid = ((q*313)+grp)*8 + b  (b=pid%8 -> XCD b; q slowest).
// Per (b,q): gather panel = 10000 x 64dims x 2B = 1.28MB << 4MB XCD L2.
// mode 0: Hnext = fp16(t)
// mode 2: Hnext = fp16((Hprev + t)*0.5)   (in-place allowed)
// mode 3: hout(f32) = (Hprev + t)*0.5     (last layer)
__global__ __launch_bounds__(256) void k_agg_q(
    const f16* __restrict__ Sup, const f16* __restrict__ Loc,
    const float* __restrict__ bias,
    const int* __restrict__ rp2, const unsigned int* __restrict__ ev,
    const f16* __restrict__ Hprev, f16* __restrict__ Hnext,
    float* __restrict__ hout, const int mode)
{
  const int pid = blockIdx.x;
  const int b = pid & 7;
  const int rest = pid >> 3;           // 0..1251
  const int grp = rest % 313;
  const int qd  = rest / 313;          // 0..3
  const int t = threadIdx.x;
  const int j = t >> 3;                // node in group (0..31)
  const int l = t & 7;
  const int n = grp * 32 + j;
  if(n >= NN) return;
  const int d0 = (qd << 6) + (l << 3);
  const size_t rb = ((size_t)b * NN + n) * 256 + d0;
  float a[8];
  {
    const f16x8 lv = *(const f16x8*)(Loc + rb);
    float4 q0 = *(const float4*)(bias + d0);
    float4 q1 = *(const float4*)(bias + d0 + 4);
    a[0] = (float)lv[0] + q0.x; a[1] = (float)lv[1] + q0.y;
    a[2] = (float)lv[2] + q0.z; a[3] = (float)lv[3] + q0.w;
    a[4] = (float)lv[4] + q1.x; a[5] = (float)lv[5] + q1.y;
    a[6] = (float)lv[6] + q1.z; a[7] = (float)lv[7] + q1.w;
  }
  const int s = rp2[n], e = rp2[n + 1];
  const size_t bb = (size_t)b * NN * 256 + d0;
  for(int i = s; i < e; i += 2){
    const u32x4 ee = *(const u32x4*)(ev + 2 * i);   // 2 edges; same addr for 8 lanes (dedup)
    const float w0 = __uint_as_float(ee[1]);
    const float w1 = __uint_as_float(ee[3]);
    const f16x8 h0 = *(const f16x8*)(Sup + bb + ((size_t)(int)ee[0]) * 256);
    const f16x8 h1 = *(const f16x8*)(Sup + bb + ((size_t)(int)ee[2]) * 256);
    #pragma unroll
    for(int d = 0; d < 8; ++d){
      a[d] = fmaf(w0, (float)h0[d], a[d]);
      a[d] = fmaf(w1, (float)h1[d], a[d]);
    }
  }
  if(mode >= 2){
    const f16x8 hp = *(const f16x8*)(Hprev + rb);
    #pragma unroll
    for(int d = 0; d < 8; ++d) a[d] = (a[d] + (float)hp[d]) * 0.5f;
  }
  if(mode == 3){
    f32x4 o0 = {a[0], a[1], a[2], a[3]};
    f32x4 o1 = {a[4], a[5], a[6], a[7]};
    *(f32x4*)(hout + rb) = o0;
    *(f32x4*)(hout + rb + 4) = o1;
    return;
  }
  f16x8 o;
  #pragma unroll
  for(int d = 0; d < 8; ++d) o[d] = (f16)a[d];
  *(f16x8*)(Hnext + rb) = o;
}

// ---------------- output layer (Dout=3), f32 throughout ----------------
__global__ __launch_bounds__(256) void k_out_sup(const float* __restrict__ h,
    const float* __restrict__ Wo, float* __restrict__ sup3){
  const int gid = blockIdx.x * 4 + (threadIdx.x >> 6);
  const int lane = threadIdx.x & 63;
  if(gid >= MROWS) return;
  const float4 v = *(const float4*)(h + (size_t)gid * 256 + lane * 4);
  const float hv[4] = {v.x, v.y, v.z, v.w};
  float p0 = 0.f, p1 = 0.f, p2 = 0.f;
  #pragma unroll
  for(int j = 0; j < 4; ++j){
    const int k = lane * 4 + j;
    p0 = fmaf(hv[j], Wo[k * 3 + 0], p0);
    p1 = fmaf(hv[j], Wo[k * 3 + 1], p1);
    p2 = fmaf(hv[j], Wo[k * 3 + 2], p2);
  }
  #pragma unroll
  for(int off = 32; off; off >>= 1){
    p0 += __shfl_xor(p0, off, 64);
    p1 += __shfl_xor(p1, off, 64);
    p2 += __shfl_xor(p2, off, 64);
  }
  if(lane == 0){
    float* o = sup3 + (size_t)gid * 3;
    o[0] = p0; o[1] = p1; o[2] = p2;
  }
}

__global__ __launch_bounds__(256) void k_out_final(const float* __restrict__ h,
    const float* __restrict__ LWo, const float* __restrict__ bo,
    const int* __restrict__ rp2, const unsigned int* __restrict__ ev,
    const float* __restrict__ sup3, float* __restrict__ out){
  const int gid = blockIdx.x * 4 + (threadIdx.x >> 6);
  const int lane = threadIdx.x & 63;
  if(gid >= MROWS) return;
  const int b = gid / NN, n = gid % NN;
  const float4 v = *(const float4*)(h + (size_t)gid * 256 + lane * 4);
  const float hv[4] = {v.x, v.y, v.z, v.w};
  float p0 = 0.f, p1 = 0.f, p2 = 0.f;
  #pragma unroll
  for(int j = 0; j < 4; ++j){
    const int k = lane * 4 + j;
    p0 = fmaf(hv[j], LWo[k * 3 + 0], p0);
    p1 = fmaf(hv[j], LWo[k * 3 + 1], p1);
    p2 = fmaf(hv[j], LWo[k * 3 + 2], p2);
  }
  const int s = rp2[n], e = rp2[n + 1];
  for(int i = s + lane; i < e; i += 64){
    const int src = (int)ev[2 * i];
    const float w = __uint_as_float(ev[2 * i + 1]);
    const float* sp = sup3 + ((size_t)b * NN + src) * 3;
    p0 = fmaf(w, sp[0], p0);
    p1 = fmaf(w, sp[1], p1);
    p2 = fmaf(w, sp[2], p2);
  }
  #pragma unroll
  for(int off = 32; off; off >>= 1){
    p0 += __shfl_xor(p0, off, 64);
    p1 += __shfl_xor(p1, off, 64);
    p2 += __shfl_xor(p2, off, 64);
  }
  if(lane == 0){
    float* o = out + (size_t)gid * 3;
    o[0] = p0 + bo[0]; o[1] = p1 + bo[1]; o[2] = p2 + bo[2];
  }
}

// ---------------- host ----------------
extern "C" void kernel_launch(void* const* d_in, const int* in_sizes, int n_in,
                              void* d_out, int out_size, void* d_ws, size_t ws_size,
                              hipStream_t stream) {
  const float* x     = (const float*)d_in[0];
  const int*   esrc  = (const int*)d_in[1];
  const int*   edst  = (const int*)d_in[2];
  const float* ew    = (const float*)d_in[3];
  const float* W_in  = (const float*)d_in[4];
  const float* LW_in = (const float*)d_in[5];
  const float* b_in  = (const float*)d_in[6];
  const float* W_blk = (const float*)d_in[7];
  const float* LW_blk= (const float*)d_in[8];
  const float* b_blk = (const float*)d_in[9];
  const float* W_out = (const float*)d_in[10];
  const float* LW_out= (const float*)d_in[11];
  const float* b_out = (const float*)d_in[12];
  const int E = in_sizes[1];

  float* outF  = (float*)d_out;
  float* xout  = outF;                  // [B,N,3]
  float* hOut  = outF + 240000;         // h region [B,N,256] f32, written at last layer
  f16* x16 = (f16*)hOut;                // doubles as fp16-x scratch before layer 0

  char* ws = (char*)d_ws;
  size_t off = 0;
  auto alloc = [&](size_t bytes) -> char* {
    char* p = ws + off;
    off += (bytes + 255) & ~(size_t)255;
    return p;
  };
  const size_t HB = (size_t)20480000 * 2;           // one fp16 activation buffer
  f16* Ha  = (f16*)alloc(HB);
  f16* Hb  = (f16*)alloc(HB);
  f16* Sup = (f16*)alloc(HB);                       // row-major [b*NN+n][256]
  f16* Loc = (f16*)alloc(HB);
  const int WTOT = 512 * 512 + 12 * 512 * 256;
  f16* Wt = (f16*)alloc((size_t)WTOT * 2);
  float* sup3    = (float*)alloc((size_t)240000 * 4);
  int*   counts  = (int*)alloc((size_t)2 * NN * 4);   // counts + cursor contiguous
  int*   cursor  = counts + NN;
  int*   rp2     = (int*)alloc((size_t)(NN + 1) * 4);
  int*   ci      = (int*)alloc((size_t)(E + NN) * 4);
  unsigned int* ev = (unsigned int*)alloc((size_t)2 * (E + NN) * 4);
  (void)ws_size; (void)n_in; (void)out_size;

  // CSR build (deterministic: rows sorted by edge id; even-padded with w=0)
  hipMemsetAsync(counts, 0, (size_t)2 * NN * 4, stream);
  k_count<<<(E + 255) / 256, 256, 0, stream>>>(edst, E, counts);
  k_scan<<<1, 1024, 0, stream>>>(counts, rp2);
  k_fill<<<(E + 255) / 256, 256, 0, stream>>>(edst, E, rp2, cursor, ci);
  k_sort_rows<<<(NN + 255) / 256, 256, 0, stream>>>(rp2, cursor, ci, ev, esrc, ew);

  // convert x -> fp16 ; pack transposed weights fp16
  k_cvt<<<(5120000 + 255) / 256, 256, 0, stream>>>((const float4*)x, (f16x8*)x16, 5120000);
  k_pack_w<<<(WTOT + 255) / 256, 256, 0, stream>>>(W_in, LW_in, W_blk, LW_blk, Wt);

  const int NBLK = 2500;    // GEMM: 1250 m-blocks x 2 (Sup/Loc)
  const int ABLK = 10016;   // agg: 4 quarters x 313 groups x 8 batches
  // layer 0 (K=512): h0 = t
  k_gemm_dual<<<NBLK, 256, 0, stream>>>(x16, Wt, Sup, Loc, 512, NBLK);
  k_agg_q<<<ABLK, 256, 0, stream>>>(Sup, Loc, b_in, rp2, ev, Ha, Ha, xout, 0);

  const f16* Wm = Wt + 512 * 512;
  for(int l = 0; l < 6; ++l){
    const int li0 = 2 * l, li1 = 2 * l + 1;
    k_gemm_dual<<<NBLK, 256, 0, stream>>>(Ha, Wm + (size_t)li0 * 131072, Sup, Loc, 256, NBLK);
    k_agg_q<<<ABLK, 256, 0, stream>>>(Sup, Loc, b_blk + li0 * 256, rp2, ev, Ha, Hb, xout, 0);
    k_gemm_dual<<<NBLK, 256, 0, stream>>>(Hb, Wm + (size_t)li1 * 131072, Sup, Loc, 256, NBLK);
    k_agg_q<<<ABLK, 256, 0, stream>>>(Sup, Loc, b_blk + li1 * 256, rp2, ev, Ha, Ha, hOut, (l == 5) ? 3 : 2);
  }

  // output layer, f32 from hOut (d_out h region)
  k_out_sup<<<MROWS / 4, 256, 0, stream>>>(hOut, W_out, sup3);
  k_out_final<<<MROWS / 4, 256, 0, stream>>>(hOut, LW_out, b_out, rp2, ev, sup3, xout);
}

// Round 15
// 1452.736 us; speedup vs baseline: 1.1375x; 1.0075x over previous
//
#include <hip/hip_runtime.h>

#define NN 10000
#define BB 8
#define MROWS 80000   // BB*NN

typedef float f32x4 __attribute__((ext_vector_type(4)));
typedef unsigned int u32x4 __attribute__((ext_vector_type(4)));
typedef _Float16 f16;
typedef _Float16 f16x8 __attribute__((ext_vector_type(8)));

typedef __attribute__((address_space(1))) void as1_void;
typedef __attribute__((address_space(3))) void as3_void;

static __device__ __forceinline__ void gl_lds16(const void* g, void* l){
  __builtin_amdgcn_global_load_lds((as1_void*)g, (as3_void*)l, 16, 0, 0);
}

// ---------------- CSR build (rows padded to even length, zero-weight pads) ----------------
__global__ void k_count(const int* __restrict__ dst, int E, int* __restrict__ counts){
  int i = blockIdx.x * blockDim.x + threadIdx.x;
  if(i < E) atomicAdd(&counts[dst[i]], 1);
}

// rp2 = exclusive scan of round-up-to-2(counts). 1024 threads x 10 serial elems.
__global__ void k_scan(const int* __restrict__ counts, int* __restrict__ rp2){
  __shared__ int buf[1024];
  const int t = threadIdx.x;
  int loc[10];
  int sum = 0;
  const int base = t * 10;
  #pragma unroll
  for(int i = 0; i < 10; ++i){
    const int idx = base + i;
    const int v = (idx < NN) ? ((counts[idx] + 1) & ~1) : 0;
    sum += v;
    loc[i] = sum;                 // inclusive local prefix
  }
  buf[t] = sum;
  __syncthreads();
  for(int off = 1; off < 1024; off <<= 1){
    const int x = (t >= off) ? buf[t - off] : 0;
    __syncthreads();
    buf[t] += x;
    __syncthreads();
  }
  const int pre = (t == 0) ? 0 : buf[t - 1];
  if(t == 0) rp2[0] = 0;
  #pragma unroll
  for(int i = 0; i < 10; ++i){
    const int idx = base + i;
    if(idx < NN) rp2[idx + 1] = pre + loc[i];
  }
}

__global__ void k_fill(const int* __restrict__ dst, int E, const int* __restrict__ rp2,
                       int* __restrict__ cursor, int* __restrict__ ci){
  int i = blockIdx.x * blockDim.x + threadIdx.x;
  if(i < E){
    int d = dst[i];
    int p = rp2[d] + atomicAdd(&cursor[d], 1);
    ci[p] = i;   // edge id; rows sorted deterministically afterwards
  }
}

// sort each row's edge ids (deterministic), emit packed (src, wbits) pairs + zero pads
__global__ void k_sort_rows(const int* __restrict__ rp2, const int* __restrict__ cursor,
                            int* __restrict__ ci, unsigned int* __restrict__ ev,
                            const int* __restrict__ esrc, const float* __restrict__ ew){
  const int n = blockIdx.x * blockDim.x + threadIdx.x;
  if(n >= NN) return;
  const int s = rp2[n];
  const int deg = cursor[n];
  const int e = s + deg;
  for(int i = s; i < e - 1; ++i){           // selection sort by edge id (unique) -> deterministic
    int mj = i, mv = ci[i];
    for(int j = i + 1; j < e; ++j){
      int v = ci[j];
      if(v < mv){ mv = v; mj = j; }
    }
    ci[mj] = ci[i]; ci[i] = mv;
  }
  for(int p = s; p < e; ++p){
    int eid = ci[p];
    ev[2 * p]     = (unsigned int)esrc[eid];
    ev[2 * p + 1] = __float_as_uint(ew[eid]);
  }
  const int e2 = rp2[n + 1];
  for(int p = e; p < e2; ++p){              // zero-weight pads (even row length)
    ev[2 * p]     = 0u;
    ev[2 * p + 1] = 0u;
  }
}

// ---------------- f32 -> fp16 convert (8 at a time) ----------------
__global__ void k_cvt(const float4* __restrict__ in, f16x8* __restrict__ out, int n8){
  int i = blockIdx.x * blockDim.x + threadIdx.x;
  if(i >= n8) return;
  float4 v0 = in[2 * i], v1 = in[2 * i + 1];
  f16x8 o;
  o[0] = (f16)v0.x; o[1] = (f16)v0.y; o[2] = (f16)v0.z; o[3] = (f16)v0.w;
  o[4] = (f16)v1.x; o[5] = (f16)v1.y; o[6] = (f16)v1.z; o[7] = (f16)v1.w;
  out[i] = o;
}

// Pack weights transposed to fp16: Wt[c][k] = W[k][c].
__global__ void k_pack_w(const float* __restrict__ Wi, const float* __restrict__ LWi,
                         const float* __restrict__ Wb, const float* __restrict__ LWb,
                         f16* __restrict__ dh){
  const int T0 = 512 * 512;
  const int TOT = T0 + 12 * 512 * 256;
  int i = blockIdx.x * blockDim.x + threadIdx.x;
  if(i >= TOT) return;
  float v;
  if(i < T0){
    int c = i >> 9, k = i & 511;
    v = (c < 256) ? Wi[k * 256 + c] : LWi[k * 256 + (c - 256)];
  } else {
    int j = i - T0;
    int li = j >> 17;          // 512*256 = 2^17
    int r = j & 131071;
    int c = r >> 8, k = r & 255;
    const float* src = (c < 256) ? (Wb + (size_t)li * 65536) : (LWb + (size_t)li * 65536);
    v = src[k * 256 + (c & 255)];
  }
  dh[i] = (f16)v;
}

// ---------------- dual GEMM (fp16): by=0 -> Sup, by=1 -> Loc ----
// BM=64, BN=256, BK=32; 40KB LDS dbuf -> 4 blocks/CU; counted vmcnt(5);
// LDS-bounce coalesced epilogue.
// XCD BATCH-AFFINITY: pid%8 = batch b -> XCD b (matches k_agg_q's pinning), so
// A (H written by agg on XCD b) is read from local L2, and Sup/Loc land on the
// XCD where the next agg gathers them. 157 m-tiles/batch (last tile partial:
// clamped loads, guarded stores). grid = 8 x 157 x 2 = 2512.
__global__ __launch_bounds__(256) void k_gemm_dual(
    const f16* __restrict__ A, const f16* __restrict__ Bt,
    f16* __restrict__ Sup, f16* __restrict__ Loc, int K)
{
  __shared__ char smem[40960];   // union: staging (As 2x4KB @0, Bs 2x16KB @8192) | bounce 33KB
  const int t = threadIdx.x;
  const int pid = blockIdx.x;
  const int b = pid & 7;               // batch == XCD (round-robin dispatch)
  const int rest = pid >> 3;           // 0..313
  const int by = rest & 1;             // 0 -> Sup, 1 -> Loc
  const int mt = rest >> 1;            // 0..156
  const int mbase = mt << 6;           // row within batch (last tile partial)
  const int n0 = by << 8;
  const int lane = t & 63, wv = t >> 6;
  const int rA = lane & 15, g = lane >> 4;
  f32x4 acc[4][4] = {};
  const int nsteps = K >> 5;
  const int rowt = t >> 2;                         // 0..63
  const int csw  = (t & 3) ^ ((rowt >> 1) & 3);    // pre-swizzled source chunk
  const int cbt  = csw << 3;                       // f16 offset 0/8/16/24
  const int rl   = mbase + rowt;
  const int rc   = (rl < NN) ? rl : (NN - 1);      // clamped A row (dup reads ok)
  const size_t arow = ((size_t)b * NN + rc) * K;

  auto STAGE = [&](int s, int buf){
    const int k0 = s << 5;
    gl_lds16(A + arow + k0 + cbt, smem + buf * 4096 + t * 16);
    #pragma unroll
    for(int qq = 0; qq < 4; ++qq){
      const size_t boff = (size_t)(n0 + qq * 64 + rowt) * K + k0 + cbt;
      gl_lds16(Bt + boff, smem + 8192 + buf * 16384 + qq * 4096 + t * 16);
    }
  };

  STAGE(0, 0);
  int cur = 0;
  const int slotx = (rA >> 1) & 3;        // read-side XOR base

  for(int s = 0; s < nsteps; ++s){
    __builtin_amdgcn_sched_barrier(0);
    if(s + 1 < nsteps){
      STAGE(s + 1, cur ^ 1);
      asm volatile("s_waitcnt vmcnt(5)" ::: "memory");
    } else {
      asm volatile("s_waitcnt vmcnt(0)" ::: "memory");
    }
    __builtin_amdgcn_s_barrier();
    __builtin_amdgcn_sched_barrier(0);

    f16x8 av[4], bv[4];
    const f16* AsC = (const f16*)(smem + cur * 4096);
    const f16* BsC = (const f16*)(smem + 8192 + cur * 16384);
    #pragma unroll
    for(int mi = 0; mi < 4; ++mi){
      const int ao = (mi * 16 + rA) * 32 + ((g ^ slotx) << 3);
      av[mi] = *(const f16x8*)(AsC + ao);
    }
    #pragma unroll
    for(int ni = 0; ni < 4; ++ni){
      const int bo = wv * 2048 + (ni * 16 + rA) * 32 + ((g ^ slotx) << 3);
      bv[ni] = *(const f16x8*)(BsC + bo);
    }
    #pragma unroll
    for(int mi = 0; mi < 4; ++mi){
      #pragma unroll
      for(int ni = 0; ni < 4; ++ni){
        acc[mi][ni] = __builtin_amdgcn_mfma_f32_16x16x32_f16(av[mi], bv[ni], acc[mi][ni], 0, 0, 0);
      }
    }
    __builtin_amdgcn_sched_barrier(0);
    __builtin_amdgcn_s_barrier();
    cur ^= 1;
  }

  // ---- LDS-bounce epilogue: acc -> padded LDS tile -> coalesced wide stores ----
  __syncthreads();                         // staging fully consumed; reuse smem
  f16* bounce = (f16*)smem;                // [64 rows][stride 264 f16] = 33 KB
  const int SP = 264;
  const int wn = wv << 6;
  #pragma unroll
  for(int mi = 0; mi < 4; ++mi){
    #pragma unroll
    for(int ni = 0; ni < 4; ++ni){
      const int col = wn + ni * 16 + rA;
      #pragma unroll
      for(int r2 = 0; r2 < 4; ++r2){
        bounce[(mi * 16 + g * 4 + r2) * SP + col] = (f16)acc[mi][ni][r2];
      }
    }
  }
  __syncthreads();
  f16* dstp = ((by == 0) ? Sup : Loc) + ((size_t)b * NN + mbase) * 256;
  #pragma unroll
  for(int rr = 0; rr < 8; ++rr){
    const int e = rr * 2048 + t * 8;
    const int row = e >> 8, col = e & 255;
    if(mbase + row < NN){
      const f16x8 v = *(const f16x8*)(bounce + row * SP + col);
      *(f16x8*)(dstp + e) = v;
    }
  }
}

// ---------------- aggregation: direct gather, XCD-batch-pinned, D-QUARTER phases -------------
// grid = 10016 blocks: pid = ((q*313)+grp)*8 + b  (b=pid%8 -> XCD b; q slowest).
// Per (b,q): gather panel = 10000 x 64dims x 2B = 1.28MB << 4MB XCD L2.
// mode 0: Hnext = fp16(t)
// mode 2: Hnext = fp16((Hprev + t)*0.5)   (in-place allowed)
// mode 3: hout(f32) = (Hprev + t)*0.5     (last layer)
__global__ __launch_bounds__(256) void k_agg_q(
    const f16* __restrict__ Sup, const f16* __restrict__ Loc,
    const float* __restrict__ bias,
    const int* __restrict__ rp2, const unsigned int* __restrict__ ev,
    const f16* __restrict__ Hprev, f16* __restrict__ Hnext,
    float* __restrict__ hout, const int mode)
{
  const int pid = blockIdx.x;
  const int b = pid & 7;
  const int rest = pid >> 3;           // 0..1251
  const int grp = rest % 313;
  const int qd  = rest / 313;          // 0..3
  const int t = threadIdx.x;
  const int j = t >> 3;                // node in group (0..31)
  const int l = t & 7;
  const int n = grp * 32 + j;
  if(n >= NN) return;
  const int d0 = (qd << 6) + (l << 3);
  const size_t rb = ((size_t)b * NN + n) * 256 + d0;
  float a[8];
  {
    const f16x8 lv = *(const f16x8*)(Loc + rb);
    float4 q0 = *(const float4*)(bias + d0);
    float4 q1 = *(const float4*)(bias + d0 + 4);
    a[0] = (float)lv[0] + q0.x; a[1] = (float)lv[1] + q0.y;
    a[2] = (float)lv[2] + q0.z; a[3] = (float)lv[3] + q0.w;
    a[4] = (float)lv[4] + q1.x; a[5] = (float)lv[5] + q1.y;
    a[6] = (float)lv[6] + q1.z; a[7] = (float)lv[7] + q1.w;
  }
  const int s = rp2[n], e = rp2[n + 1];
  const size_t bb = (size_t)b * NN * 256 + d0;
  for(int i = s; i < e; i += 2){
    const u32x4 ee = *(const u32x4*)(ev + 2 * i);   // 2 edges; same addr for 8 lanes (dedup)
    const float w0 = __uint_as_float(ee[1]);
    const float w1 = __uint_as_float(ee[3]);
    const f16x8 h0 = *(const f16x8*)(Sup + bb + ((size_t)(int)ee[0]) * 256);
    const f16x8 h1 = *(const f16x8*)(Sup + bb + ((size_t)(int)ee[2]) * 256);
    #pragma unroll
    for(int d = 0; d < 8; ++d){
      a[d] = fmaf(w0, (float)h0[d], a[d]);
      a[d] = fmaf(w1, (float)h1[d], a[d]);
    }
  }
  if(mode >= 2){
    const f16x8 hp = *(const f16x8*)(Hprev + rb);
    #pragma unroll
    for(int d = 0; d < 8; ++d) a[d] = (a[d] + (float)hp[d]) * 0.5f;
  }
  if(mode == 3){
    f32x4 o0 = {a[0], a[1], a[2], a[3]};
    f32x4 o1 = {a[4], a[5], a[6], a[7]};
    *(f32x4*)(hout + rb) = o0;
    *(f32x4*)(hout + rb + 4) = o1;
    return;
  }
  f16x8 o;
  #pragma unroll
  for(int d = 0; d < 8; ++d) o[d] = (f16)a[d];
  *(f16x8*)(Hnext + rb) = o;
}

// ---------------- output layer (Dout=3), f32 throughout ----------------
__global__ __launch_bounds__(256) void k_out_sup(const float* __restrict__ h,
    const float* __restrict__ Wo, float* __restrict__ sup3){
  const int gid = blockIdx.x * 4 + (threadIdx.x >> 6);
  const int lane = threadIdx.x & 63;
  if(gid >= MROWS) return;
  const float4 v = *(const float4*)(h + (size_t)gid * 256 + lane * 4);
  const float hv[4] = {v.x, v.y, v.z, v.w};
  float p0 = 0.f, p1 = 0.f, p2 = 0.f;
  #pragma unroll
  for(int j = 0; j < 4; ++j){
    const int k = lane * 4 + j;
    p0 = fmaf(hv[j], Wo[k * 3 + 0], p0);
    p1 = fmaf(hv[j], Wo[k * 3 + 1], p1);
    p2 = fmaf(hv[j], Wo[k * 3 + 2], p2);
  }
  #pragma unroll
  for(int off = 32; off; off >>= 1){
    p0 += __shfl_xor(p0, off, 64);
    p1 += __shfl_xor(p1, off, 64);
    p2 += __shfl_xor(p2, off, 64);
  }
  if(lane == 0){
    float* o = sup3 + (size_t)gid * 3;
    o[0] = p0; o[1] = p1; o[2] = p2;
  }
}

__global__ __launch_bounds__(256) void k_out_final(const float* __restrict__ h,
    const float* __restrict__ LWo, const float* __restrict__ bo,
    const int* __restrict__ rp2, const unsigned int* __restrict__ ev,
    const float* __restrict__ sup3, float* __restrict__ out){
  const int gid = blockIdx.x * 4 + (threadIdx.x >> 6);
  const int lane = threadIdx.x & 63;
  if(gid >= MROWS) return;
  const int b = gid / NN, n = gid % NN;
  const float4 v = *(const float4*)(h + (size_t)gid * 256 + lane * 4);
  const float hv[4] = {v.x, v.y, v.z, v.w};
  float p0 = 0.f, p1 = 0.f, p2 = 0.f;
  #pragma unroll
  for(int j = 0; j < 4; ++j){
    const int k = lane * 4 + j;
    p0 = fmaf(hv[j], LWo[k * 3 + 0], p0);
    p1 = fmaf(hv[j], LWo[k * 3 + 1], p1);
    p2 = fmaf(hv[j], LWo[k * 3 + 2], p2);
  }
  const int s = rp2[n], e = rp2[n + 1];
  for(int i = s + lane; i < e; i += 64){
    const int src = (int)ev[2 * i];
    const float w = __uint_as_float(ev[2 * i + 1]);
    const float* sp = sup3 + ((size_t)b * NN + src) * 3;
    p0 = fmaf(w, sp[0], p0);
    p1 = fmaf(w, sp[1], p1);
    p2 = fmaf(w, sp[2], p2);
  }
  #pragma unroll
  for(int off = 32; off; off >>= 1){
    p0 += __shfl_xor(p0, off, 64);
    p1 += __shfl_xor(p1, off, 64);
    p2 += __shfl_xor(p2, off, 64);
  }
  if(lane == 0){
    float* o = out + (size_t)gid * 3;
    o[0] = p0 + bo[0]; o[1] = p1 + bo[1]; o[2] = p2 + bo[2];
  }
}

// ---------------- host ----------------
extern "C" void kernel_launch(void* const* d_in, const int* in_sizes, int n_in,
                              void* d_out, int out_size, void* d_ws, size_t ws_size,
                              hipStream_t stream) {
  const float* x     = (const float*)d_in[0];
  const int*   esrc  = (const int*)d_in[1];
  const int*   edst  = (const int*)d_in[2];
  const float* ew    = (const float*)d_in[3];
  const float* W_in  = (const float*)d_in[4];
  const float* LW_in = (const float*)d_in[5];
  const float* b_in  = (const float*)d_in[6];
  const float* W_blk = (const float*)d_in[7];
  const float* LW_blk= (const float*)d_in[8];
  const float* b_blk = (const float*)d_in[9];
  const float* W_out = (const float*)d_in[10];
  const float* LW_out= (const float*)d_in[11];
  const float* b_out = (const float*)d_in[12];
  const int E = in_sizes[1];

  float* outF  = (float*)d_out;
  float* xout  = outF;                  // [B,N,3]
  float* hOut  = outF + 240000;         // h region [B,N,256] f32, written at last layer
  f16* x16 = (f16*)hOut;                // doubles as fp16-x scratch before layer 0

  char* ws = (char*)d_ws;
  size_t off = 0;
  auto alloc = [&](size_t bytes) -> char* {
    char* p = ws + off;
    off += (bytes + 255) & ~(size_t)255;
    return p;
  };
  const size_t HB = (size_t)20480000 * 2;           // one fp16 activation buffer
  f16* Ha  = (f16*)alloc(HB);
  f16* Hb  = (f16*)alloc(HB);
  f16* Sup = (f16*)alloc(HB);                       // row-major [b*NN+n][256]
  f16* Loc = (f16*)alloc(HB);
  const int WTOT = 512 * 512 + 12 * 512 * 256;
  f16* Wt = (f16*)alloc((size_t)WTOT * 2);
  float* sup3    = (float*)alloc((size_t)240000 * 4);
  int*   counts  = (int*)alloc((size_t)2 * NN * 4);   // counts + cursor contiguous
  int*   cursor  = counts + NN;
  int*   rp2     = (int*)alloc((size_t)(NN + 1) * 4);
  int*   ci      = (int*)alloc((size_t)(E + NN) * 4);
  unsigned int* ev = (unsigned int*)alloc((size_t)2 * (E + NN) * 4);
  (void)ws_size; (void)n_in; (void)out_size;

  // CSR build (deterministic: rows sorted by edge id; even-padded with w=0)
  hipMemsetAsync(counts, 0, (size_t)2 * NN * 4, stream);
  k_count<<<(E + 255) / 256, 256, 0, stream>>>(edst, E, counts);
  k_scan<<<1, 1024, 0, stream>>>(counts, rp2);
  k_fill<<<(E + 255) / 256, 256, 0, stream>>>(edst, E, rp2, cursor, ci);
  k_sort_rows<<<(NN + 255) / 256, 256, 0, stream>>>(rp2, cursor, ci, ev, esrc, ew);

  // convert x -> fp16 ; pack transposed weights fp16
  k_cvt<<<(5120000 + 255) / 256, 256, 0, stream>>>((const float4*)x, (f16x8*)x16, 5120000);
  k_pack_w<<<(WTOT + 255) / 256, 256, 0, stream>>>(W_in, LW_in, W_blk, LW_blk, Wt);

  const int NBLK = 2512;    // GEMM: 8 batches x 157 m-tiles x 2 (Sup/Loc)
  const int ABLK = 10016;   // agg: 4 quarters x 313 groups x 8 batches
  // layer 0 (K=512): h0 = t
  k_gemm_dual<<<NBLK, 256, 0, stream>>>(x16, Wt, Sup, Loc, 512);
  k_agg_q<<<ABLK, 256, 0, stream>>>(Sup, Loc, b_in, rp2, ev, Ha, Ha, xout, 0);

  const f16* Wm = Wt + 512 * 512;
  for(int l = 0; l < 6; ++l){
    const int li0 = 2 * l, li1 = 2 * l + 1;
    k_gemm_dual<<<NBLK, 256, 0, stream>>>(Ha, Wm + (size_t)li0 * 131072, Sup, Loc, 256);
    k_agg_q<<<ABLK, 256, 0, stream>>>(Sup, Loc, b_blk + li0 * 256, rp2, ev, Ha, Hb, xout, 0);
    k_gemm_dual<<<NBLK, 256, 0, stream>>>(Hb, Wm + (size_t)li1 * 131072, Sup, Loc, 256);
    k_agg_q<<<ABLK, 256, 0, stream>>>(Sup, Loc, b_blk + li1 * 256, rp2, ev, Ha, Ha, hOut, (l == 5) ? 3 : 2);
  }

  // output layer, f32 from hOut (d_out h region)
  k_out_sup<<<MROWS / 4, 256, 0, stream>>>(hOut, W_out, sup3);
  k_out_final<<<MROWS / 4, 256, 0, stream>>>(hOut, LW_out, b_out, rp2, ev, sup3, xout);
}